// Round 11
// baseline (160.332 us; speedup 1.0000x reference)
//
#include <hip/hip_runtime.h>
#include <hip/hip_bf16.h>

// Problem constants
#define B_    8
#define CIN   128
#define H_    64
#define W_    64
#define COUT  128
#define K_    16
#define HO    61
#define WO    61
#define HW_   (HO * WO)          // 3721

typedef short bf16x8 __attribute__((ext_vector_type(8)));
typedef short s16x4  __attribute__((ext_vector_type(4)));
typedef int   s32x4  __attribute__((ext_vector_type(4)));
typedef float f32x4  __attribute__((ext_vector_type(4)));
typedef float f32x2  __attribute__((ext_vector_type(2)));
typedef float f32x4u __attribute__((ext_vector_type(4), aligned(4)));

// lgkm-only barrier: LDS writes drained, vmem queue stays in flight.
#define RAWBAR() asm volatile("s_waitcnt lgkmcnt(0)\n\ts_barrier" ::: "memory")

// ---------------------------------------------------------------------------
// Fused prep: blocks 0..511 transpose input [b][c][y][x] f32 -> T[b][y*64+x][c]
// bf16 (1 MB/batch, XCD-L2 resident); blocks 512..639 repack weight.
// Weight layout (fragment-major, pre-flipped, kk = k*128 + c):
//   A2[((blk*64 + it)*64 + lane)*8 + j];  o = blk*16 + (lane&15);
//   kk = it*32 + (lane>>4)*8 + j;  k = kk>>7;  c = kk&127.
__global__ __launch_bounds__(256) void prep_all(const float* __restrict__ inp,
                                                const float* __restrict__ w,
                                                __hip_bfloat16* __restrict__ T,
                                                __hip_bfloat16* __restrict__ A2) {
    const int t = threadIdx.x;
    if (blockIdx.x < 512) {
        __shared__ float ld[64][129];      // pad 129: conflict-free both phases
        const int b  = blockIdx.x >> 6;
        const int sb = (blockIdx.x & 63) << 6;   // 64-spatial slab
        const float* src = inp + ((size_t)b << 19);
        #pragma unroll
        for (int i = 0; i < 8; ++i) {
            int j  = i * 256 + t;
            int c  = j >> 4;
            int s4 = (j & 15) << 2;
            f32x4u v = *(const f32x4u*)(const void*)(src + ((size_t)c << 12) + sb + s4);
            #pragma unroll
            for (int q = 0; q < 4; ++q) ld[s4 + q][c] = v[q];
        }
        __syncthreads();
        __hip_bfloat16* dst = T + (((size_t)b << 12) + sb) * 128;
        #pragma unroll
        for (int i = 0; i < 8; ++i) {
            int j  = i * 256 + t;
            int s  = j >> 5;
            int c4 = (j & 31) << 2;
            s16x4 v;
            #pragma unroll
            for (int q = 0; q < 4; ++q) {
                __hip_bfloat16 hh = __float2bfloat16(ld[s][c4 + q]);
                v[q] = *reinterpret_cast<const short*>(&hh);
            }
            *(s16x4*)(void*)(dst + (size_t)s * 128 + c4) = v;
        }
    } else {
        int gid  = (blockIdx.x - 512) * 256 + t;   // 32768 threads
        int lane = gid & 63;
        int it   = (gid >> 6) & 63;
        int blk  = gid >> 12;
        int o    = blk * 16 + (lane & 15);
        int kk   = it * 32 + (lane >> 4) * 8;      // never crosses c=128
        int k    = kk >> 7;
        int c0   = kk & 127;
        const float* srcw = w + (((size_t)(o << 7) + c0) << 4) + (15 - k);
        __hip_bfloat16* dst = A2 + (size_t)gid * 8;
        #pragma unroll
        for (int j = 0; j < 8; ++j)
            dst[j] = __float2bfloat16(srcw[j << 4]);   // c = c0+j, same k
    }
}

// ---------------------------------------------------------------------------
// Main: block = ONE OUTPUT ROW (64 px incl. 3 pad) x 128 couts, 8 waves.
// Round-11 vs round 10: LDS diet for occupancy.  Params packed: pw as one
// f32x4 (single ds_read_b128) and pb as two u16 in one dword (offsets <= 4094
// fit u16; single ds_read_b32).  LDS 56 KB -> 52 KB => 3 blocks/CU
// (24 waves, 6/SIMD, +50% TLP vs r10's 16) — r10's ledger showed 4 pipes at
// 34-47% each with imperfect overlap = TLP starvation.  VGPR 60 <= 85 cap
// at 6 waves/SIMD, no spill risk.  Dataflow bit-identical to r10.
__global__ __launch_bounds__(512, 6) void deform_gather(
        const __hip_bfloat16* __restrict__ T, const float* __restrict__ off,
        const float* __restrict__ msk, const __hip_bfloat16* __restrict__ A2,
        const float* __restrict__ bias, float* __restrict__ out) {

    __shared__ __align__(16) __hip_bfloat16 Bs[2][64 * 128];  // 2 x 16 KB
    __shared__ __align__(16) f32x4    pwq[1024];              // 16 KB bilinear w
    __shared__ unsigned               pbq[1024];              // 4 KB packed offs

    const int t   = threadIdx.x;
    const int bid = blockIdx.x;
    const int b   = bid & 7;               // batch<->XCD pinning (488 % 8 == 0)
    const int ho  = bid >> 3;

    // ---- phase 0: exact per-(pixel,tap) bilinear params -> LDS (1024 pairs) ----
    #pragma unroll
    for (int ii = 0; ii < 2; ++ii) {
        const int idx = ii * 512 + t;      // = k*64 + px
        const int px  = idx & 63;
        const int k   = idx >> 6;
        const bool pvalid = (px < WO);
        const int wo_c = pvalid ? px : (WO - 1);
        const int r    = ho * WO + wo_c;
        const int ki = k >> 2, kj = k & 3;
        const size_t offb = (size_t)b * (2 * K_ * HW_);
        float dy = off[offb + (size_t)(2 * k)     * HW_ + r];
        float dx = off[offb + (size_t)(2 * k + 1) * HW_ + r];
        float mm = msk[(size_t)b * (K_ * HW_) + (size_t)k * HW_ + r];
        if (!pvalid) mm = 0.0f;

        float y   = dy + (float)(ki + ho);
        float x   = dx + (float)(kj + wo_c);
        float y0f = floorf(y), x0f = floorf(x);
        float wy  = y - y0f,   wx  = x - x0f;
        int y0 = (int)y0f, x0 = (int)x0f;
        int y1 = y0 + 1,   x1 = x0 + 1;

        float wy0v = (1.0f - wy) * ((y0 >= 0 && y0 < H_) ? mm : 0.0f);
        float wy1v = wy          * ((y1 >= 0 && y1 < H_) ? mm : 0.0f);
        int cy0 = min(max(y0, 0), H_ - 1), cy1 = min(max(y1, 0), H_ - 1);

        float wx0v = (1.0f - wx) * ((x0 >= 0 && x0 < W_) ? 1.0f : 0.0f);
        float wx1v = wx          * ((x1 >= 0 && x1 < W_) ? 1.0f : 0.0f);
        int xb = min(max(x0, 0), W_ - 2);
        int tsh = x0 - xb;                 // -1,0,1 (else both x-weights 0)
        float a0 = (tsh == 0) ? wx0v : ((tsh == -1) ? wx1v : 0.0f);
        float a1 = (tsh == 0) ? wx1v : ((tsh ==  1) ? wx0v : 0.0f);

        f32x4 wq = { wy0v * a0, wy0v * a1, wy1v * a0, wy1v * a1 };
        pwq[idx] = wq;
        pbq[idx] = (unsigned)(cy0 * W_ + xb) | ((unsigned)(cy1 * W_ + xb) << 16);
    }
    __syncthreads();                       // params visible (full drain ok, once)

    const int lane = t & 63;
    const int wv   = t >> 6;               // 0..7 = cout-block
    const int p_g  = lane >> 2;            // gather pair-pixel within px-group
    const int mrow = lane & 15;            // MFMA pixel col
    const int quad = lane >> 4;
    const __hip_bfloat16* Tb = T + ((size_t)b << 19);

    // this wave's 2 gather units per phase: u = 2*wv + i -> (px-group, ch-group)
    int rowU[2], cbU[2], swzU[2];
    #pragma unroll
    for (int i = 0; i < 2; ++i) {
        const int u = (wv << 1) + i;
        rowU[i] = ((u >> 2) << 4) + p_g;               // px = pg*16 + p_g
        cbU[i]  = ((u & 3) << 5) + ((lane & 3) << 3);  // ch base 0..127
        swzU[i] = (rowU[i] << 7) + (((cbU[i] >> 3) ^ (rowU[i] & 7)) << 3);
    }

    f32x4 accA = {0.f,0.f,0.f,0.f}, accB = {0.f,0.f,0.f,0.f};
    f32x4 accC = {0.f,0.f,0.f,0.f}, accD = {0.f,0.f,0.f,0.f};

    s32x4 cU[2][4];                        // single gather buffer (r8 dataflow)
    bf16x8 avR[4];

    // gather 2 units for tap qp: 8 dwordx4, one fully-used 64B line each
    auto uget = [&](int qp) {
        #pragma unroll
        for (int i = 0; i < 2; ++i) {
            const int pidx = (qp << 6) + rowU[i];
            const unsigned pk = pbq[pidx];             // one ds_read_b32
            const __hip_bfloat16* p0 = Tb + ((pk & 0xffffu) << 7) + cbU[i];
            const __hip_bfloat16* p1 = Tb + ((pk >> 16) << 7)     + cbU[i];
            cU[i][0] = *(const s32x4*)(const void*)(p0);          // (y0,x0)
            cU[i][1] = *(const s32x4*)(const void*)(p0 + 128);    // (y0,x1)
            cU[i][2] = *(const s32x4*)(const void*)(p1);          // (y1,x0)
            cU[i][3] = *(const s32x4*)(const void*)(p1 + 128);    // (y1,x1)
        }
    };

    // combine: packed f32x2 bilinear (mul+fma+fma+fma per element, identical
    // chain to rounds 5-10 -> bit-identical), then 2 x ds_write_b128
    auto ucomb = [&](int qp) {
        const int bb_ = qp & 1;
        #pragma unroll
        for (int i = 0; i < 2; ++i) {
            const int pidx = (qp << 6) + rowU[i];
            const f32x4 wq = pwq[pidx];                // one ds_read_b128
            const float w0 = wq[0], w1 = wq[1], w2 = wq[2], w3 = wq[3];
            bf16x8 v;
            #pragma unroll
            for (int jj = 0; jj < 4; ++jj) {
                const unsigned a = (unsigned)cU[i][0][jj];
                const unsigned bq = (unsigned)cU[i][1][jj];
                const unsigned c = (unsigned)cU[i][2][jj];
                const unsigned d = (unsigned)cU[i][3][jj];
                f32x2 va = { __uint_as_float(a << 16),  __uint_as_float(a & 0xffff0000u) };
                f32x2 vb = { __uint_as_float(bq << 16), __uint_as_float(bq & 0xffff0000u) };
                f32x2 vc = { __uint_as_float(c << 16),  __uint_as_float(c & 0xffff0000u) };
                f32x2 vd = { __uint_as_float(d << 16),  __uint_as_float(d & 0xffff0000u) };
                f32x2 s = va * w0;
                s += vb * w1;
                s += vc * w2;
                s += vd * w3;
                __hip_bfloat16 h0 = __float2bfloat16(s[0]);
                __hip_bfloat16 h1 = __float2bfloat16(s[1]);
                v[2*jj]   = *reinterpret_cast<const short*>(&h0);
                v[2*jj+1] = *reinterpret_cast<const short*>(&h1);
            }
            *(bf16x8*)(void*)(&Bs[bb_][swzU[i]]) = v;
        }
    };

    // A-fragments for one tap (4 x bf16x8 = 16 VGPR), cout-block = wv
    auto loadA = [&](int qp) {
        #pragma unroll
        for (int s_ = 0; s_ < 4; ++s_) {
            avR[s_] = *(const bf16x8*)(const void*)(
                A2 + ((size_t)((wv * 64 + qp * 4 + s_) * 64 + lane) << 3));
        }
    };

    auto mfma_exec = [&](int qp) {
        const int bb_ = qp & 1;
        const int mx = mrow & 7;
        #pragma unroll
        for (int s_ = 0; s_ < 4; ++s_) {
            const int colX = ((((s_ << 2) + quad) ^ mx) << 3);   // lane-const
            const int i0 = (mrow << 7) + colX;
            const int i1 = ((16 + mrow) << 7) + colX;
            const int i2 = ((32 + mrow) << 7) + colX;
            const int i3 = ((48 + mrow) << 7) + colX;
            bf16x8 b0 = *(const bf16x8*)(const void*)(&Bs[bb_][i0]);
            bf16x8 b1 = *(const bf16x8*)(const void*)(&Bs[bb_][i1]);
            bf16x8 b2 = *(const bf16x8*)(const void*)(&Bs[bb_][i2]);
            bf16x8 b3 = *(const bf16x8*)(const void*)(&Bs[bb_][i3]);
            accA = __builtin_amdgcn_mfma_f32_16x16x32_bf16(avR[s_], b0, accA, 0, 0, 0);
            accB = __builtin_amdgcn_mfma_f32_16x16x32_bf16(avR[s_], b1, accB, 0, 0, 0);
            accC = __builtin_amdgcn_mfma_f32_16x16x32_bf16(avR[s_], b2, accC, 0, 0, 0);
            accD = __builtin_amdgcn_mfma_f32_16x16x32_bf16(avR[s_], b3, accD, 0, 0, 0);
        }
    };

    // prologue: tap 0 (the one uncovered gather stall)
    uget(0);
    ucomb(0);
    loadA(0);
    RAWBAR();                              // Bs[0] visible; loadA(0) in flight

    #pragma unroll 1
    for (int qp = 1; qp < 16; ++qp) {
        uget(qp);                          // 8 gather loads, issued first
        __builtin_amdgcn_s_setprio(1);
        mfma_exec(qp - 1);                 // ds_read+MFMA overlap TA queue
        __builtin_amdgcn_s_setprio(0);
        loadA(qp);                         // crosses the barrier in flight
        ucomb(qp);                         // counted vmcnt wait on gathers only
        RAWBAR();                          // lgkm-only drain
    }
    mfma_exec(15);

    // ---- epilogue: C/D col = mrow (pixel), row = quad*4 + jj (cout) ----
    #pragma unroll
    for (int pg = 0; pg < 4; ++pg) {
        const int px = (pg << 4) + mrow;
        if (px < WO) {
            const size_t outb = (size_t)b * (COUT * HW_) + (size_t)(ho * WO + px);
            const f32x4 a = (pg == 0) ? accA : (pg == 1) ? accB
                          : (pg == 2) ? accC : accD;
            #pragma unroll
            for (int jj = 0; jj < 4; ++jj) {
                const int o = wv * 16 + quad * 4 + jj;
                out[outb + (size_t)o * HW_] = a[jj] + bias[o];
            }
        }
    }
}

extern "C" void kernel_launch(void* const* d_in, const int* in_sizes, int n_in,
                              void* d_out, int out_size, void* d_ws, size_t ws_size,
                              hipStream_t stream) {
    const float* inp  = (const float*)d_in[0];
    const float* off  = (const float*)d_in[1];
    const float* msk  = (const float*)d_in[2];
    const float* wgt  = (const float*)d_in[3];
    const float* bias = (const float*)d_in[4];
    float* out = (float*)d_out;

    __hip_bfloat16* A2 = (__hip_bfloat16*)d_ws;                       // 512 KB
    __hip_bfloat16* T  = (__hip_bfloat16*)((char*)d_ws + (1 << 20));  // 8 MB

    prep_all<<<640, 256, 0, stream>>>(inp, wgt, T, A2);

    int nblk = B_ * HO;                    // 488, bid&7 = batch
    deform_gather<<<nblk, 512, 0, stream>>>(T, off, msk, A2, bias, out);
}

// Round 12
// 113.201 us; speedup vs baseline: 1.4163x; 1.4163x over previous
//
#include <hip/hip_runtime.h>
#include <hip/hip_bf16.h>

// Problem constants
#define B_    8
#define CIN   128
#define H_    64
#define W_    64
#define COUT  128
#define K_    16
#define HO    61
#define WO    61
#define HW_   (HO * WO)          // 3721

typedef short bf16x8 __attribute__((ext_vector_type(8)));
typedef short s16x4  __attribute__((ext_vector_type(4)));
typedef int   s32x4  __attribute__((ext_vector_type(4)));
typedef float f32x4  __attribute__((ext_vector_type(4)));
typedef float f32x2  __attribute__((ext_vector_type(2)));
typedef float f32x4u __attribute__((ext_vector_type(4), aligned(4)));

// lgkm-only barrier: LDS writes drained, vmem queue stays in flight.
#define RAWBAR() asm volatile("s_waitcnt lgkmcnt(0)\n\ts_barrier" ::: "memory")

// ---------------------------------------------------------------------------
// Fused prep: blocks 0..511 transpose input [b][c][y][x] f32 -> T[b][y*64+x][c]
// bf16 (1 MB/batch, XCD-L2 resident); blocks 512..639 repack weight.
// Weight layout (fragment-major, pre-flipped, kk = k*128 + c):
//   A2[((blk*64 + it)*64 + lane)*8 + j];  o = blk*16 + (lane&15);
//   kk = it*32 + (lane>>4)*8 + j;  k = kk>>7;  c = kk&127.
__global__ __launch_bounds__(256) void prep_all(const float* __restrict__ inp,
                                                const float* __restrict__ w,
                                                __hip_bfloat16* __restrict__ T,
                                                __hip_bfloat16* __restrict__ A2) {
    const int t = threadIdx.x;
    if (blockIdx.x < 512) {
        __shared__ float ld[64][129];      // pad 129: conflict-free both phases
        const int b  = blockIdx.x >> 6;
        const int sb = (blockIdx.x & 63) << 6;   // 64-spatial slab
        const float* src = inp + ((size_t)b << 19);
        #pragma unroll
        for (int i = 0; i < 8; ++i) {
            int j  = i * 256 + t;
            int c  = j >> 4;
            int s4 = (j & 15) << 2;
            f32x4u v = *(const f32x4u*)(const void*)(src + ((size_t)c << 12) + sb + s4);
            #pragma unroll
            for (int q = 0; q < 4; ++q) ld[s4 + q][c] = v[q];
        }
        __syncthreads();
        __hip_bfloat16* dst = T + (((size_t)b << 12) + sb) * 128;
        #pragma unroll
        for (int i = 0; i < 8; ++i) {
            int j  = i * 256 + t;
            int s  = j >> 5;
            int c4 = (j & 31) << 2;
            s16x4 v;
            #pragma unroll
            for (int q = 0; q < 4; ++q) {
                __hip_bfloat16 hh = __float2bfloat16(ld[s][c4 + q]);
                v[q] = *reinterpret_cast<const short*>(&hh);
            }
            *(s16x4*)(void*)(dst + (size_t)s * 128 + c4) = v;
        }
    } else {
        int gid  = (blockIdx.x - 512) * 256 + t;   // 32768 threads
        int lane = gid & 63;
        int it   = (gid >> 6) & 63;
        int blk  = gid >> 12;
        int o    = blk * 16 + (lane & 15);
        int kk   = it * 32 + (lane >> 4) * 8;      // never crosses c=128
        int k    = kk >> 7;
        int c0   = kk & 127;
        const float* srcw = w + (((size_t)(o << 7) + c0) << 4) + (15 - k);
        __hip_bfloat16* dst = A2 + (size_t)gid * 8;
        #pragma unroll
        for (int j = 0; j < 8; ++j)
            dst[j] = __float2bfloat16(srcw[j << 4]);   // c = c0+j, same k
    }
}

// ---------------------------------------------------------------------------
// Main: block = ONE OUTPUT ROW (64 px incl. 3 pad) x 128 couts, 8 waves.
// Round-12 = round-11's LDS diet (52 KB: packed pwq f32x4 + pbq u16-pair;
// enables 3 blocks/CU = 24 waves) with round-10's PROVEN launch bounds
// (512,4).  r11's (512,6) tightened the VGPR cap to ~84 and the allocator
// collapsed to 40 VGPR + catastrophic scratch (WRITE_SIZE 139 MB, 2x dur).
// Lesson: occupancy must come from actual resource use; the bounds arg past
// natural pressure triggers spill.  Dataflow bit-identical to r8-r11.
__global__ __launch_bounds__(512, 4) void deform_gather(
        const __hip_bfloat16* __restrict__ T, const float* __restrict__ off,
        const float* __restrict__ msk, const __hip_bfloat16* __restrict__ A2,
        const float* __restrict__ bias, float* __restrict__ out) {

    __shared__ __align__(16) __hip_bfloat16 Bs[2][64 * 128];  // 2 x 16 KB
    __shared__ __align__(16) f32x4    pwq[1024];              // 16 KB bilinear w
    __shared__ unsigned               pbq[1024];              // 4 KB packed offs

    const int t   = threadIdx.x;
    const int bid = blockIdx.x;
    const int b   = bid & 7;               // batch<->XCD pinning (488 % 8 == 0)
    const int ho  = bid >> 3;

    // ---- phase 0: exact per-(pixel,tap) bilinear params -> LDS (1024 pairs) ----
    #pragma unroll
    for (int ii = 0; ii < 2; ++ii) {
        const int idx = ii * 512 + t;      // = k*64 + px
        const int px  = idx & 63;
        const int k   = idx >> 6;
        const bool pvalid = (px < WO);
        const int wo_c = pvalid ? px : (WO - 1);
        const int r    = ho * WO + wo_c;
        const int ki = k >> 2, kj = k & 3;
        const size_t offb = (size_t)b * (2 * K_ * HW_);
        float dy = off[offb + (size_t)(2 * k)     * HW_ + r];
        float dx = off[offb + (size_t)(2 * k + 1) * HW_ + r];
        float mm = msk[(size_t)b * (K_ * HW_) + (size_t)k * HW_ + r];
        if (!pvalid) mm = 0.0f;

        float y   = dy + (float)(ki + ho);
        float x   = dx + (float)(kj + wo_c);
        float y0f = floorf(y), x0f = floorf(x);
        float wy  = y - y0f,   wx  = x - x0f;
        int y0 = (int)y0f, x0 = (int)x0f;
        int y1 = y0 + 1,   x1 = x0 + 1;

        float wy0v = (1.0f - wy) * ((y0 >= 0 && y0 < H_) ? mm : 0.0f);
        float wy1v = wy          * ((y1 >= 0 && y1 < H_) ? mm : 0.0f);
        int cy0 = min(max(y0, 0), H_ - 1), cy1 = min(max(y1, 0), H_ - 1);

        float wx0v = (1.0f - wx) * ((x0 >= 0 && x0 < W_) ? 1.0f : 0.0f);
        float wx1v = wx          * ((x1 >= 0 && x1 < W_) ? 1.0f : 0.0f);
        int xb = min(max(x0, 0), W_ - 2);
        int tsh = x0 - xb;                 // -1,0,1 (else both x-weights 0)
        float a0 = (tsh == 0) ? wx0v : ((tsh == -1) ? wx1v : 0.0f);
        float a1 = (tsh == 0) ? wx1v : ((tsh ==  1) ? wx0v : 0.0f);

        f32x4 wq = { wy0v * a0, wy0v * a1, wy1v * a0, wy1v * a1 };
        pwq[idx] = wq;
        pbq[idx] = (unsigned)(cy0 * W_ + xb) | ((unsigned)(cy1 * W_ + xb) << 16);
    }
    __syncthreads();                       // params visible (full drain ok, once)

    const int lane = t & 63;
    const int wv   = t >> 6;               // 0..7 = cout-block
    const int p_g  = lane >> 2;            // gather pair-pixel within px-group
    const int mrow = lane & 15;            // MFMA pixel col
    const int quad = lane >> 4;
    const __hip_bfloat16* Tb = T + ((size_t)b << 19);

    // this wave's 2 gather units per phase: u = 2*wv + i -> (px-group, ch-group)
    int rowU[2], cbU[2], swzU[2];
    #pragma unroll
    for (int i = 0; i < 2; ++i) {
        const int u = (wv << 1) + i;
        rowU[i] = ((u >> 2) << 4) + p_g;               // px = pg*16 + p_g
        cbU[i]  = ((u & 3) << 5) + ((lane & 3) << 3);  // ch base 0..127
        swzU[i] = (rowU[i] << 7) + (((cbU[i] >> 3) ^ (rowU[i] & 7)) << 3);
    }

    f32x4 accA = {0.f,0.f,0.f,0.f}, accB = {0.f,0.f,0.f,0.f};
    f32x4 accC = {0.f,0.f,0.f,0.f}, accD = {0.f,0.f,0.f,0.f};

    s32x4 cU[2][4];                        // single gather buffer (r8 dataflow)
    bf16x8 avR[4];

    // gather 2 units for tap qp: 8 dwordx4, one fully-used 64B line each
    auto uget = [&](int qp) {
        #pragma unroll
        for (int i = 0; i < 2; ++i) {
            const int pidx = (qp << 6) + rowU[i];
            const unsigned pk = pbq[pidx];             // one ds_read_b32
            const __hip_bfloat16* p0 = Tb + ((pk & 0xffffu) << 7) + cbU[i];
            const __hip_bfloat16* p1 = Tb + ((pk >> 16) << 7)     + cbU[i];
            cU[i][0] = *(const s32x4*)(const void*)(p0);          // (y0,x0)
            cU[i][1] = *(const s32x4*)(const void*)(p0 + 128);    // (y0,x1)
            cU[i][2] = *(const s32x4*)(const void*)(p1);          // (y1,x0)
            cU[i][3] = *(const s32x4*)(const void*)(p1 + 128);    // (y1,x1)
        }
    };

    // combine: packed f32x2 bilinear (mul+fma+fma+fma per element, identical
    // chain to rounds 5-11 -> bit-identical), then 2 x ds_write_b128
    auto ucomb = [&](int qp) {
        const int bb_ = qp & 1;
        #pragma unroll
        for (int i = 0; i < 2; ++i) {
            const int pidx = (qp << 6) + rowU[i];
            const f32x4 wq = pwq[pidx];                // one ds_read_b128
            const float w0 = wq[0], w1 = wq[1], w2 = wq[2], w3 = wq[3];
            bf16x8 v;
            #pragma unroll
            for (int jj = 0; jj < 4; ++jj) {
                const unsigned a = (unsigned)cU[i][0][jj];
                const unsigned bq = (unsigned)cU[i][1][jj];
                const unsigned c = (unsigned)cU[i][2][jj];
                const unsigned d = (unsigned)cU[i][3][jj];
                f32x2 va = { __uint_as_float(a << 16),  __uint_as_float(a & 0xffff0000u) };
                f32x2 vb = { __uint_as_float(bq << 16), __uint_as_float(bq & 0xffff0000u) };
                f32x2 vc = { __uint_as_float(c << 16),  __uint_as_float(c & 0xffff0000u) };
                f32x2 vd = { __uint_as_float(d << 16),  __uint_as_float(d & 0xffff0000u) };
                f32x2 s = va * w0;
                s += vb * w1;
                s += vc * w2;
                s += vd * w3;
                __hip_bfloat16 h0 = __float2bfloat16(s[0]);
                __hip_bfloat16 h1 = __float2bfloat16(s[1]);
                v[2*jj]   = *reinterpret_cast<const short*>(&h0);
                v[2*jj+1] = *reinterpret_cast<const short*>(&h1);
            }
            *(bf16x8*)(void*)(&Bs[bb_][swzU[i]]) = v;
        }
    };

    // A-fragments for one tap (4 x bf16x8 = 16 VGPR), cout-block = wv
    auto loadA = [&](int qp) {
        #pragma unroll
        for (int s_ = 0; s_ < 4; ++s_) {
            avR[s_] = *(const bf16x8*)(const void*)(
                A2 + ((size_t)((wv * 64 + qp * 4 + s_) * 64 + lane) << 3));
        }
    };

    auto mfma_exec = [&](int qp) {
        const int bb_ = qp & 1;
        const int mx = mrow & 7;
        #pragma unroll
        for (int s_ = 0; s_ < 4; ++s_) {
            const int colX = ((((s_ << 2) + quad) ^ mx) << 3);   // lane-const
            const int i0 = (mrow << 7) + colX;
            const int i1 = ((16 + mrow) << 7) + colX;
            const int i2 = ((32 + mrow) << 7) + colX;
            const int i3 = ((48 + mrow) << 7) + colX;
            bf16x8 b0 = *(const bf16x8*)(const void*)(&Bs[bb_][i0]);
            bf16x8 b1 = *(const bf16x8*)(const void*)(&Bs[bb_][i1]);
            bf16x8 b2 = *(const bf16x8*)(const void*)(&Bs[bb_][i2]);
            bf16x8 b3 = *(const bf16x8*)(const void*)(&Bs[bb_][i3]);
            accA = __builtin_amdgcn_mfma_f32_16x16x32_bf16(avR[s_], b0, accA, 0, 0, 0);
            accB = __builtin_amdgcn_mfma_f32_16x16x32_bf16(avR[s_], b1, accB, 0, 0, 0);
            accC = __builtin_amdgcn_mfma_f32_16x16x32_bf16(avR[s_], b2, accC, 0, 0, 0);
            accD = __builtin_amdgcn_mfma_f32_16x16x32_bf16(avR[s_], b3, accD, 0, 0, 0);
        }
    };

    // prologue: tap 0 (the one uncovered gather stall)
    uget(0);
    ucomb(0);
    loadA(0);
    RAWBAR();                              // Bs[0] visible; loadA(0) in flight

    #pragma unroll 1
    for (int qp = 1; qp < 16; ++qp) {
        uget(qp);                          // 8 gather loads, issued first
        __builtin_amdgcn_s_setprio(1);
        mfma_exec(qp - 1);                 // ds_read+MFMA overlap TA queue
        __builtin_amdgcn_s_setprio(0);
        loadA(qp);                         // crosses the barrier in flight
        ucomb(qp);                         // counted vmcnt wait on gathers only
        RAWBAR();                          // lgkm-only drain
    }
    mfma_exec(15);

    // ---- epilogue: C/D col = mrow (pixel), row = quad*4 + jj (cout) ----
    #pragma unroll
    for (int pg = 0; pg < 4; ++pg) {
        const int px = (pg << 4) + mrow;
        if (px < WO) {
            const size_t outb = (size_t)b * (COUT * HW_) + (size_t)(ho * WO + px);
            const f32x4 a = (pg == 0) ? accA : (pg == 1) ? accB
                          : (pg == 2) ? accC : accD;
            #pragma unroll
            for (int jj = 0; jj < 4; ++jj) {
                const int o = wv * 16 + quad * 4 + jj;
                out[outb + (size_t)o * HW_] = a[jj] + bias[o];
            }
        }
    }
}

extern "C" void kernel_launch(void* const* d_in, const int* in_sizes, int n_in,
                              void* d_out, int out_size, void* d_ws, size_t ws_size,
                              hipStream_t stream) {
    const float* inp  = (const float*)d_in[0];
    const float* off  = (const float*)d_in[1];
    const float* msk  = (const float*)d_in[2];
    const float* wgt  = (const float*)d_in[3];
    const float* bias = (const float*)d_in[4];
    float* out = (float*)d_out;

    __hip_bfloat16* A2 = (__hip_bfloat16*)d_ws;                       // 512 KB
    __hip_bfloat16* T  = (__hip_bfloat16*)((char*)d_ws + (1 << 20));  // 8 MB

    prep_all<<<640, 256, 0, stream>>>(inp, wgt, T, A2);

    int nblk = B_ * HO;                    // 488, bid&7 = batch
    deform_gather<<<nblk, 512, 0, stream>>>(T, off, msk, A2, bias, out);
}